// Round 4
// baseline (297.630 us; speedup 1.0000x reference)
//
#include <hip/hip_runtime.h>

// ---------------------------------------------------------------------------
// TPA attention, factorized to GQA flash attention.
// B=1, S=2048, HID=2048, H=16, KVH=8, D=128, QR=6, KR=2, VR=2
// ---------------------------------------------------------------------------

constexpr int SEQ   = 2048;
constexpr int HIDN  = 2048;
constexpr int NHEAD = 16;
constexpr int NKVH  = 8;
constexpr int DH    = 128;
constexpr int NCOLS = 1408;   // 96 Aq | 16 Ak | 16 Av | 768 Bq | 256 Bk | 256 Bv

typedef __bf16 bf16x8 __attribute__((ext_vector_type(8)));
typedef float  f32x4  __attribute__((ext_vector_type(4)));

#define MFMA(a, b, c) __builtin_amdgcn_mfma_f32_16x16x32_bf16((a), (b), (c), 0, 0, 0)

__device__ __forceinline__ void gload_lds16(const void* g, void* l) {
  __builtin_amdgcn_global_load_lds(
      (const __attribute__((address_space(1))) void*)g,
      (__attribute__((address_space(3))) void*)l, 16, 0, 0);
}

// ---- pack / convert -------------------------------------------------------

__global__ __launch_bounds__(256) void k_cvt_bf16(const float* __restrict__ x,
                                                  __bf16* __restrict__ y, int n) {
  int i = blockIdx.x * 256 + threadIdx.x;
  if (i < n) y[i] = (__bf16)x[i];
}

// W_all^T [1408][2048] bf16 so the GEMM B-operand reads K-contiguous rows.
__global__ __launch_bounds__(256) void k_pack_wall(
    const float* __restrict__ WAq, const float* __restrict__ WAk,
    const float* __restrict__ WAv, const float* __restrict__ WBq,
    const float* __restrict__ WBk, const float* __restrict__ WBv,
    __bf16* __restrict__ WT) {
  int i = blockIdx.x * 256 + threadIdx.x;  // i < 1408*2048
  int c = i >> 11, k = i & 2047;
  float v;
  if (c < 96)        v = WAq[k * 96 + c];
  else if (c < 112)  v = WAk[k * 16 + (c - 96)];
  else if (c < 128)  v = WAv[k * 16 + (c - 112)];
  else if (c < 896)  v = WBq[k * 768 + (c - 128)];
  else if (c < 1152) v = WBk[k * 256 + (c - 896)];
  else               v = WBv[k * 256 + (c - 1152)];
  WT[i] = (__bf16)v;
}

// Wo^T [2048][2048] bf16 via LDS tile transpose (coalesced both sides).
__global__ __launch_bounds__(256) void k_pack_wo(const float* __restrict__ Wo,
                                                 __bf16* __restrict__ WoT) {
  __shared__ float t[32][33];
  int bn = blockIdx.x * 32, bk = blockIdx.y * 32;
  int tx = threadIdx.x & 31, ty = threadIdx.x >> 5;  // ty 0..7
  for (int j = 0; j < 32; j += 8)
    t[ty + j][tx] = Wo[(size_t)(bk + ty + j) * HIDN + bn + tx];
  __syncthreads();
  for (int j = 0; j < 32; j += 8)
    WoT[(size_t)(bn + ty + j) * HIDN + bk + tx] = (__bf16)t[tx][ty + j];
}

// ---- GEMM: C[M][N] = A[M][K] * BT[N][K]^T, bf16 in, f32 out ---------------
// 128(M)x64(N) tile, 4 waves (2x2), BK=32, global_load_lds staging.

__global__ __launch_bounds__(256) void k_gemm_bt(const __bf16* __restrict__ A,
                                                 const __bf16* __restrict__ BT,
                                                 float* __restrict__ C,
                                                 int M, int N, int K) {
  __shared__ __bf16 As[4096];  // [128 rows][32 k] linear
  __shared__ __bf16 Bs[2048];  // [64 cols][32 k] linear
  const int tid = threadIdx.x;
  const int w = tid >> 6, lane = tid & 63;
  const int lhi = lane >> 4, llo = lane & 15;
  const int wr = w >> 1, wc = w & 1;
  const int brow = blockIdx.y * 128, bcol = blockIdx.x * 64;
  const int rA = lane >> 2, kA = (lane & 3) * 8;  // lane -> (row-in-seg, k-seg)

  f32x4 acc[4][2];
#pragma unroll
  for (int m = 0; m < 4; m++)
#pragma unroll
    for (int n = 0; n < 2; n++) acc[m][n] = (f32x4){0.f, 0.f, 0.f, 0.f};

  for (int k0 = 0; k0 < K; k0 += 32) {
#pragma unroll
    for (int i = 0; i < 2; i++) {
      int seg = w * 2 + i;           // 8 segs of 1KB for A
      int row = seg * 16 + rA;
      gload_lds16(A + (size_t)(brow + row) * K + k0 + kA, &As[seg * 512]);
    }
    gload_lds16(BT + (size_t)(bcol + w * 16 + rA) * K + k0 + kA, &Bs[w * 512]);
    __syncthreads();
    bf16x8 af[4], bfr[2];
#pragma unroll
    for (int m = 0; m < 4; m++)
      af[m] = *(const bf16x8*)&As[(wr * 64 + m * 16 + llo) * 32 + lhi * 8];
#pragma unroll
    for (int n = 0; n < 2; n++)
      bfr[n] = *(const bf16x8*)&Bs[(wc * 32 + n * 16 + llo) * 32 + lhi * 8];
#pragma unroll
    for (int m = 0; m < 4; m++)
#pragma unroll
      for (int n = 0; n < 2; n++) acc[m][n] = MFMA(af[m], bfr[n], acc[m][n]);
    __syncthreads();
  }
#pragma unroll
  for (int m = 0; m < 4; m++)
#pragma unroll
    for (int n = 0; n < 2; n++) {
      int r0 = brow + wr * 64 + m * 16 + lhi * 4;
      int c0 = bcol + wc * 32 + n * 16 + llo;
#pragma unroll
      for (int r = 0; r < 4; r++) C[(size_t)(r0 + r) * N + c0] = acc[m][n][r];
    }
}

// ---- build Q/K/Vt from projections (rope + rank contraction) --------------

__global__ __launch_bounds__(128) void k_build_qkv(const float* __restrict__ P,
                                                   const float* __restrict__ cosT,
                                                   const float* __restrict__ sinT,
                                                   __bf16* __restrict__ Qo,
                                                   __bf16* __restrict__ Ko,
                                                   __bf16* __restrict__ Vto) {
  const int q = blockIdx.x, d = threadIdx.x;  // 128 threads
  __shared__ float Ash[128];                  // Aq(96) | Ak(16) | Av(16)
  const float* row = P + (size_t)q * NCOLS;
  Ash[d] = row[d];
  __syncthreads();
  const int m2 = (d >> 1) * 2;
  const bool odd = d & 1;
  const float c = cosT[q * 64 + (d >> 1)];
  const float s = sinT[q * 64 + (d >> 1)];

  float qacc[16];
#pragma unroll
  for (int h = 0; h < 16; h++) qacc[h] = 0.f;
#pragma unroll
  for (int r = 0; r < 6; r++) {
    float xe = row[128 + r * 128 + m2];
    float xo = row[128 + r * 128 + m2 + 1];
    float br = odd ? (xe * s + xo * c) : (xe * c - xo * s);
#pragma unroll
    for (int h = 0; h < 16; h++) qacc[h] += Ash[h * 6 + r] * br;
  }
#pragma unroll
  for (int h = 0; h < 16; h++)
    Qo[((size_t)h * SEQ + q) * DH + d] = (__bf16)(qacc[h] * 0.08838834764831845f);

  float kacc[8];
#pragma unroll
  for (int g = 0; g < 8; g++) kacc[g] = 0.f;
#pragma unroll
  for (int ss = 0; ss < 2; ss++) {
    float xe = row[896 + ss * 128 + m2];
    float xo = row[896 + ss * 128 + m2 + 1];
    float bs = odd ? (xe * s + xo * c) : (xe * c - xo * s);
#pragma unroll
    for (int g = 0; g < 8; g++) kacc[g] += Ash[96 + g * 2 + ss] * bs;
  }
#pragma unroll
  for (int g = 0; g < 8; g++)
    Ko[((size_t)g * SEQ + q) * DH + d] = (__bf16)kacc[g];

  float vacc[8];
#pragma unroll
  for (int g = 0; g < 8; g++) vacc[g] = 0.f;
#pragma unroll
  for (int u = 0; u < 2; u++) {
    float vu = row[1152 + u * 128 + d];
#pragma unroll
    for (int g = 0; g < 8; g++) vacc[g] += Ash[112 + g * 2 + u] * vu;
  }
#pragma unroll
  for (int g = 0; g < 8; g++)
    Vto[((size_t)g * DH + d) * SEQ + q] = (__bf16)vacc[g];
}

// ---- flash attention, wave-independent ------------------------------------
// 512 blocks x 4 waves; each WAVE independently owns (16 q-rows, head):
// no barriers, no K/V LDS (K/V = 8MB total, L2/L1-resident; staging it was
// pure lockstep overhead). Per tile: K,V frags straight from global into
// MFMA regs (V issued early, hides under QK+softmax). P transpose through
// per-wave private LDS (wave-coherent, no barrier). Fixed-max softmax.
// Decode: raw&7 = group (dispatch round-robins id%8 -> XCD), so each XCD's
// L2 holds its group's 1MB K/V; heavy q-blocks first within each stripe.

__global__ __launch_bounds__(256) void k_attn(const __bf16* __restrict__ Q,
                                              const __bf16* __restrict__ Kc,
                                              const __bf16* __restrict__ Vt,
                                              __bf16* __restrict__ AO) {
  const int raw = blockIdx.x;
  const int g = raw & 7;
  const int j = raw >> 3;             // 0..63
  const int h = g * 2 + (j & 1);
  const int bqi = 31 - (j >> 1);      // heavy first
  const int w = threadIdx.x >> 6, lane = threadIdx.x & 63;
  const int lhi = lane >> 4, llo = lane & 15;
  const int q0 = bqi * 64 + w * 16;
  const int nt = (q0 >> 5) + 1;       // 32-key tiles covering keys <= q0+15

  __shared__ __bf16 Plds[4][512];     // per-wave private 16x32 P tile, swizzled
  __bf16* Pl = Plds[w];

  const __bf16* Qh = Q  + (size_t)h * SEQ * DH;
  const __bf16* Kg = Kc + (size_t)g * SEQ * DH;
  const __bf16* Vg = Vt + (size_t)g * DH * SEQ;

  bf16x8 aq[4];
#pragma unroll
  for (int c = 0; c < 4; c++)
    aq[c] = *(const bf16x8*)&Qh[(size_t)(q0 + llo) * DH + c * 32 + lhi * 8];

  f32x4 oacc[8];
  float lsum[4] = {0.f, 0.f, 0.f, 0.f};
#pragma unroll
  for (int n = 0; n < 8; n++) oacc[n] = (f32x4){0.f, 0.f, 0.f, 0.f};

  for (int t = 0; t < nt; t++) {
    const int kb = t * 32;
    // K frags (needed first), then V frags (consumed after softmax — their
    // latency hides under QK MFMA + softcap ALU).
    bf16x8 kf[8];
#pragma unroll
    for (int c = 0; c < 4; c++) {
      kf[c * 2]     = *(const bf16x8*)&Kg[(size_t)(kb + llo) * DH + c * 32 + lhi * 8];
      kf[c * 2 + 1] = *(const bf16x8*)&Kg[(size_t)(kb + 16 + llo) * DH + c * 32 + lhi * 8];
    }
    bf16x8 vf[8];
#pragma unroll
    for (int n = 0; n < 8; n++)
      vf[n] = *(const bf16x8*)&Vg[(size_t)(n * 16 + llo) * SEQ + kb + lhi * 8];

    f32x4 s0 = {0.f, 0.f, 0.f, 0.f}, s1 = {0.f, 0.f, 0.f, 0.f};
#pragma unroll
    for (int c = 0; c < 4; c++) {
      s0 = MFMA(aq[c], kf[c * 2], s0);
      s1 = MFMA(aq[c], kf[c * 2 + 1], s1);
    }
#pragma unroll
    for (int r = 0; r < 4; r++) {
      const int qrow = q0 + lhi * 4 + r;
      const int rho = lhi * 4 + r;
      // w = exp(50*tanh(v/50)) = exp2(72.135 - 144.27/(e^{v/25}+1));
      // range [e^-50, e^50] — f32-safe, exact softmax after normalize.
      float t0e = exp2f(s0[r] * 0.057707802f);
      float t1e = exp2f(s1[r] * 0.057707802f);
      float p0 = exp2f(72.134752f - 144.269504f * __builtin_amdgcn_rcpf(t0e + 1.f));
      float p1 = exp2f(72.134752f - 144.269504f * __builtin_amdgcn_rcpf(t1e + 1.f));
      if (kb + llo > qrow) p0 = 0.f;
      if (kb + 16 + llo > qrow) p1 = 0.f;
      lsum[r] += p0 + p1;
      const int sw = ((rho >> 1) & 3) << 4;
      *(__bf16*)((char*)Pl + rho * 64 + ((llo * 2) ^ sw))      = (__bf16)p0;
      *(__bf16*)((char*)Pl + rho * 64 + ((llo * 2 + 32) ^ sw)) = (__bf16)p1;
    }
    bf16x8 pa = *(const bf16x8*)((const char*)Pl + llo * 64 +
                                 ((lhi * 16) ^ (((llo >> 1) & 3) << 4)));
#pragma unroll
    for (int n = 0; n < 8; n++) oacc[n] = MFMA(pa, vf[n], oacc[n]);
  }

#pragma unroll
  for (int r = 0; r < 4; r++) {
    float tsum = lsum[r];
    tsum += __shfl_xor(tsum, 1);
    tsum += __shfl_xor(tsum, 2);
    tsum += __shfl_xor(tsum, 4);
    tsum += __shfl_xor(tsum, 8);
    const float inv = 1.f / tsum;
    const int qrow = q0 + lhi * 4 + r;
#pragma unroll
    for (int n = 0; n < 8; n++)
      AO[(size_t)qrow * HIDN + h * DH + n * 16 + llo] = (__bf16)(oacc[n][r] * inv);
  }
}

// ---------------------------------------------------------------------------

extern "C" void kernel_launch(void* const* d_in, const int* in_sizes, int n_in,
                              void* d_out, int out_size, void* d_ws, size_t ws_size,
                              hipStream_t stream) {
  const float* hidden = (const float*)d_in[0];
  const float* cosT   = (const float*)d_in[1];
  const float* sinT   = (const float*)d_in[2];
  // d_in[3] = mask (pure causal, computed analytically), d_in[4] = arange (unused)
  const float* WAq = (const float*)d_in[5];
  const float* WAk = (const float*)d_in[6];
  const float* WAv = (const float*)d_in[7];
  const float* WBq = (const float*)d_in[8];
  const float* WBk = (const float*)d_in[9];
  const float* WBv = (const float*)d_in[10];
  const float* Wo  = (const float*)d_in[11];
  float* out = (float*)d_out;

  // Workspace layout, ~59.2 MB total (known-good size):
  char* ws = (char*)d_ws;
  __bf16* hid_bf = (__bf16*)(ws);                    //  8,388,608
  __bf16* WallT  = (__bf16*)(ws + 8388608);          //  5,767,168
  float*  Pproj  = (float*)(ws + 14155776);          // 11,534,336
  __bf16* WoT    = (__bf16*)(ws + 25690112);         //  8,388,608
  __bf16* Qb     = (__bf16*)(ws + 34078720);         //  8,388,608
  __bf16* Kb     = (__bf16*)(ws + 42467328);         //  4,194,304
  __bf16* Vt     = (__bf16*)(ws + 46661632);         //  4,194,304
  __bf16* AO     = (__bf16*)(ws + 50855936);         //  8,388,608

  k_cvt_bf16<<<(SEQ * HIDN) / 256, 256, 0, stream>>>(hidden, hid_bf, SEQ * HIDN);
  k_pack_wall<<<(NCOLS * HIDN) / 256, 256, 0, stream>>>(WAq, WAk, WAv, WBq, WBk, WBv, WallT);
  k_pack_wo<<<dim3(64, 64), 256, 0, stream>>>(Wo, WoT);
  k_gemm_bt<<<dim3(NCOLS / 64, SEQ / 128), 256, 0, stream>>>(hid_bf, WallT, Pproj,
                                                             SEQ, NCOLS, HIDN);
  k_build_qkv<<<SEQ, 128, 0, stream>>>(Pproj, cosT, sinT, Qb, Kb, Vt);
  k_attn<<<512, 256, 0, stream>>>(Qb, Kb, Vt, AO);
  k_gemm_bt<<<dim3(HIDN / 64, SEQ / 128), 256, 0, stream>>>(AO, WoT, out,
                                                            SEQ, HIDN, HIDN);
}